// Round 1
// baseline (180.303 us; speedup 1.0000x reference)
//
#include <hip/hip_runtime.h>
#include <cfloat>

typedef __attribute__((ext_vector_type(8))) short short8;
typedef __attribute__((ext_vector_type(4))) float f32x4;

#define NE 1024
#define EDIM 256
#define HW 1024
#define BSTRIDE (EDIM * HW)        // 262144
#define TOTAL 8388608

// workspace layout (bytes)
#define EMBB_OFF  0                        // ushort[1024*256] bf16 = 512 KB
#define ENORM_OFF (512 * 1024)             // float[1024]
#define HIST_OFF  (ENORM_OFF + 4096)       // int[1024]
#define LOSS_OFF  (HIST_OFF + 4096)        // float accumulator

// round-to-nearest-even fp32 -> bf16 bits (inputs are finite)
__device__ __forceinline__ unsigned short f2bf(float x) {
    unsigned u = __builtin_bit_cast(unsigned, x);
    return (unsigned short)((u + 0x7fffu + ((u >> 16) & 1u)) >> 16);
}

// ---------------------------------------------------------------------------
// P: emb fp32 [1024][256] -> embB bf16 rows + enorm. 64 blocks x 256 thr,
// 16 threads per code row (16-elem segment each), shfl-reduce the norm.
// Block 0 also zeroes hist + loss accumulator (replaces the memset dispatch).
// ---------------------------------------------------------------------------
__global__ void prep_emb(const float* __restrict__ emb,
                         unsigned short* __restrict__ embB,
                         float* __restrict__ enorm,
                         int* __restrict__ hist,
                         float* __restrict__ lossAcc) {
    int t = threadIdx.x;
    int gid = blockIdx.x * 256 + t;        // 0..16383
    int row = gid >> 4, seg = gid & 15;
    const float4* e4 = (const float4*)(emb + (size_t)row * EDIM) + seg * 4;
    float4 a0 = e4[0], a1 = e4[1], a2 = e4[2], a3 = e4[3];
    float s = a0.x * a0.x + a0.y * a0.y + a0.z * a0.z + a0.w * a0.w
            + a1.x * a1.x + a1.y * a1.y + a1.z * a1.z + a1.w * a1.w
            + a2.x * a2.x + a2.y * a2.y + a2.z * a2.z + a2.w * a2.w
            + a3.x * a3.x + a3.y * a3.y + a3.z * a3.z + a3.w * a3.w;
    short8 v0, v1;
    v0[0] = (short)f2bf(a0.x); v0[1] = (short)f2bf(a0.y);
    v0[2] = (short)f2bf(a0.z); v0[3] = (short)f2bf(a0.w);
    v0[4] = (short)f2bf(a1.x); v0[5] = (short)f2bf(a1.y);
    v0[6] = (short)f2bf(a1.z); v0[7] = (short)f2bf(a1.w);
    v1[0] = (short)f2bf(a2.x); v1[1] = (short)f2bf(a2.y);
    v1[2] = (short)f2bf(a2.z); v1[3] = (short)f2bf(a2.w);
    v1[4] = (short)f2bf(a3.x); v1[5] = (short)f2bf(a3.y);
    v1[6] = (short)f2bf(a3.z); v1[7] = (short)f2bf(a3.w);
    *(short8*)&embB[(size_t)row * EDIM + seg * 16]     = v0;
    *(short8*)&embB[(size_t)row * EDIM + seg * 16 + 8] = v1;
    s += __shfl_xor(s, 1, 64);
    s += __shfl_xor(s, 2, 64);
    s += __shfl_xor(s, 4, 64);
    s += __shfl_xor(s, 8, 64);
    if (seg == 0) enorm[row] = s;
    if (blockIdx.x == 0) {                 // fold memset into this dispatch
        ((int4*)hist)[t] = (int4){0, 0, 0, 0};
        if (t == 0) lossAcc[0] = 0.f;
    }
}

// ---------------------------------------------------------------------------
// F: fused argmin + gather + loss + hist. Block = 64 positions, 512 threads
// (8 waves), grid 512. LDS ~76 KB -> 2 blocks/CU -> 16 waves/CU (50% occ cap,
// vs 8 waves/CU before: the kernel was latency-bound at ~1.2 KB in flight/CU).
// Wave (mw,nw): mw = 32-position half (2 m-frags, A in regs), nw = 32-code
// quarter of each 128-code N-tile (B staged in LDS, shared by all 8 waves).
// Epilogue: stage selected fp32 emb rows into LDS [c][p-quad float4 slots],
// write z_q coalesced float4, loss from L2-hot z re-read, hist atomics.
// ---------------------------------------------------------------------------
__global__ __launch_bounds__(512, 4) void fused_kernel(
        const float* __restrict__ z, const float* __restrict__ emb,
        const unsigned short* __restrict__ embB, const float* __restrict__ enormG,
        float* __restrict__ zq, int* __restrict__ hist,
        float* __restrict__ lossAcc) {
    // union buffer: As 64x264 bf16 (33.8 KB) / Bs 128x264 bf16 (67.6 KB)
    //             / Es 256x17 float4 (69.6 KB)
    __shared__ __align__(16) char smem[256 * 17 * 16];
    __shared__ float Ens[NE];
    __shared__ float rv[4][64];
    __shared__ int   ri[4][64];
    __shared__ int   idxm[64];

    unsigned short* As = (unsigned short*)smem;
    unsigned short* Bs = (unsigned short*)smem;
    short8*        Bs8 = (short8*)smem;
    float4*         Es = (float4*)smem;
    float*         Esf = (float*)smem;

    int t = threadIdx.x;                   // 0..511
    int m0 = blockIdx.x * 64;
    int b = m0 >> 10, pb = m0 & 1023;
    const float* zb  = z  + (size_t)b * BSTRIDE + pb;
    float*       zqb = zq + (size_t)b * BSTRIDE + pb;

    for (int j = t; j < NE; j += 512) Ens[j] = enormG[j];

    {   // stage A: float4 loads along p (8x16B in flight/thread), packed
        // short8 LDS writes. thread = (p-quad pq, 8-channel group cg).
        int pq = t & 15, cg = t >> 4;      // cg 0..31
        const float* zp = zb + pq * 4;
        float4 zv[8];
#pragma unroll
        for (int u = 0; u < 8; ++u)
            zv[u] = *(const float4*)&zp[(size_t)(cg * 8 + u) * HW];
#pragma unroll
        for (int j = 0; j < 4; ++j) {
            short8 v;
#pragma unroll
            for (int u = 0; u < 8; ++u) {
                float x = (j == 0) ? zv[u].x : (j == 1) ? zv[u].y
                        : (j == 2) ? zv[u].z : zv[u].w;
                v[u] = (short)f2bf(x);
            }
            *(short8*)&As[(pq * 4 + j) * 264 + cg * 8] = v;
        }
    }
    __syncthreads();

    int w = t >> 6, l = t & 63, lm = l & 15, q = l >> 4;
    int mw = w >> 2, nw = w & 3;           // mw 0..1 (32-pos half), nw 0..3

    short8 A[2][8];
#pragma unroll
    for (int s = 0; s < 2; ++s)
#pragma unroll
        for (int ks = 0; ks < 8; ++ks)
            A[s][ks] = *(const short8*)&As[(mw * 32 + s * 16 + lm) * 264 + ks * 32 + q * 8];

    float bd[8]; int bi[8];
#pragma unroll
    for (int i = 0; i < 8; ++i) { bd[i] = FLT_MAX; bi[i] = 0x7fffffff; }

    __syncthreads();   // A consumed; smem becomes the B tile buffer

    const short8* eB8 = (const short8*)embB;
    for (int nt = 0; nt < 8; ++nt) {
        int n0 = nt * 128;
        // stage B tile: 128 code rows x 256 k = 4096 short8 over 512 threads
#pragma unroll
        for (int i = 0; i < 8; ++i) {
            int ch = i * 512 + t;
            int row = ch >> 5, k8 = ch & 31;
            Bs8[row * 33 + k8] = eB8[(size_t)(n0 + row) * 32 + k8];
        }
        __syncthreads();
#pragma unroll
        for (int nf = 0; nf < 2; ++nf) {
            int cl = nw * 32 + nf * 16 + lm;      // local code row in tile
            float en = Ens[n0 + cl];
            f32x4 a0a = {0,0,0,0}, a0b = {0,0,0,0};
            f32x4 a1a = {0,0,0,0}, a1b = {0,0,0,0};
#pragma unroll
            for (int ks = 0; ks < 8; ks += 2) {
                short8 Bv0 = *(const short8*)&Bs[cl * 264 + ks * 32 + q * 8];
                short8 Bv1 = *(const short8*)&Bs[cl * 264 + (ks + 1) * 32 + q * 8];
                a0a = __builtin_amdgcn_mfma_f32_16x16x32_bf16(A[0][ks],     Bv0, a0a, 0, 0, 0);
                a1a = __builtin_amdgcn_mfma_f32_16x16x32_bf16(A[1][ks],     Bv0, a1a, 0, 0, 0);
                a0b = __builtin_amdgcn_mfma_f32_16x16x32_bf16(A[0][ks + 1], Bv1, a0b, 0, 0, 0);
                a1b = __builtin_amdgcn_mfma_f32_16x16x32_bf16(A[1][ks + 1], Bv1, a1b, 0, 0, 0);
            }
            int code = n0 + cl;
#pragma unroll
            for (int r = 0; r < 4; ++r) {
                float d0 = en - 2.f * (a0a[r] + a0b[r]);
                if (d0 < bd[r])     { bd[r] = d0;     bi[r] = code; }
                float d1 = en - 2.f * (a1a[r] + a1b[r]);
                if (d1 < bd[4 + r]) { bd[4 + r] = d1; bi[4 + r] = code; }
            }
        }
        __syncthreads();   // B tile consumed
    }

    // reduce across the 16 code-columns (lanes sharing q)
#pragma unroll
    for (int off = 1; off < 16; off <<= 1) {
#pragma unroll
        for (int i = 0; i < 8; ++i) {
            float od = __shfl_xor(bd[i], off, 64);
            int   oi = __shfl_xor(bi[i], off, 64);
            if (od < bd[i] || (od == bd[i] && oi < bi[i])) { bd[i] = od; bi[i] = oi; }
        }
    }
    if (lm == 0) {
#pragma unroll
        for (int s = 0; s < 2; ++s)
#pragma unroll
            for (int r = 0; r < 4; ++r) {
                int p = mw * 32 + s * 16 + q * 4 + r;
                rv[nw][p] = bd[s * 4 + r];
                ri[nw][p] = bi[s * 4 + r];
            }
    }
    __syncthreads();
    if (t < 64) {
        float v = rv[0][t]; int bix = ri[0][t];
#pragma unroll
        for (int j = 1; j < 4; ++j) {
            float vj = rv[j][t]; int ij = ri[j][t];
            if (vj < v || (vj == v && ij < bix)) { v = vj; bix = ij; }
        }
        idxm[t] = bix;
        atomicAdd(&hist[bix], 1);
    }
    __syncthreads();

    {   // stage selected fp32 emb rows: position r, eighth qo (8 float4 each)
        int r = t >> 3, qo = t & 7;
        int kr = idxm[r];
        const float4* er = (const float4*)(emb + (size_t)kr * EDIM);
        int base = (r >> 2) * 4 + (r & 3);     // dword offset within c-row
#pragma unroll
        for (int u = 0; u < 8; ++u) {
            float4 v = er[qo * 8 + u];
            int c = (qo * 8 + u) * 4;
            Esf[(c + 0) * 68 + base] = v.x;
            Esf[(c + 1) * 68 + base] = v.y;
            Esf[(c + 2) * 68 + base] = v.z;
            Esf[(c + 3) * 68 + base] = v.w;
        }
    }
    __syncthreads();

    {   // z_q write + loss: thread = (p-quad, 8 channels)
        int pq = t & 15, cg2 = t >> 4;     // cg2 0..31
        float ls = 0.f;
#pragma unroll
        for (int cc = 0; cc < 8; ++cc) {
            int c = cg2 * 8 + cc;
            float4 zv = *(const float4*)&zb[(size_t)c * HW + pq * 4];
            float4 ev = Es[c * 17 + pq];
            *(float4*)&zqb[(size_t)c * HW + pq * 4] = ev;
            float dx = ev.x - zv.x, dy = ev.y - zv.y;
            float dz = ev.z - zv.z, dw = ev.w - zv.w;
            ls += dx * dx + dy * dy + dz * dz + dw * dw;
        }
#pragma unroll
        for (int off = 32; off; off >>= 1) ls += __shfl_down(ls, off, 64);
        if ((t & 63) == 0) atomicAdd(lossAcc, ls);
    }
}

// ---------------------------------------------------------------------------
// Z: finalize loss + perplexity into d_out tail.
// ---------------------------------------------------------------------------
__global__ void finalize_kernel(const int* __restrict__ hist,
                                const float* __restrict__ lossAcc,
                                float* __restrict__ out) {
    __shared__ float wsum[4];
    int t = threadIdx.x;
    float s = 0.f;
    for (int j = t; j < NE; j += 256) {
        float p = (float)hist[j] * (1.0f / 32768.0f);
        s += p * logf(p + 1e-10f);
    }
#pragma unroll
    for (int off = 32; off; off >>= 1) s += __shfl_down(s, off, 64);
    if ((t & 63) == 0) wsum[t >> 6] = s;
    __syncthreads();
    if (t == 0) {
        float S = wsum[0] + wsum[1] + wsum[2] + wsum[3];
        out[TOTAL]     = 1.25f * lossAcc[0] / (float)TOTAL;
        out[TOTAL + 1] = expf(-S);
    }
}

extern "C" void kernel_launch(void* const* d_in, const int* in_sizes, int n_in,
                              void* d_out, int out_size, void* d_ws, size_t ws_size,
                              hipStream_t stream) {
    (void)in_sizes; (void)n_in; (void)out_size; (void)ws_size;
    const float* z   = (const float*)d_in[0];
    const float* emb = (const float*)d_in[1];
    float* out = (float*)d_out;
    char* ws = (char*)d_ws;
    unsigned short* embB = (unsigned short*)(ws + EMBB_OFF);
    float* enorm   = (float*)(ws + ENORM_OFF);
    int*   hist    = (int*)(ws + HIST_OFF);
    float* lossAcc = (float*)(ws + LOSS_OFF);

    prep_emb<<<64, 256, 0, stream>>>(emb, embB, enorm, hist, lossAcc);
    fused_kernel<<<512, 512, 0, stream>>>(z, emb, embB, enorm, out, hist, lossAcc);
    finalize_kernel<<<1, 256, 0, stream>>>(hist, lossAcc, out);
}

// Round 2
// 178.855 us; speedup vs baseline: 1.0081x; 1.0081x over previous
//
#include <hip/hip_runtime.h>
#include <cfloat>

typedef __attribute__((ext_vector_type(8))) short short8;
typedef __attribute__((ext_vector_type(4))) float f32x4;

#define NE 1024
#define EDIM 256
#define HW 1024
#define BSTRIDE (EDIM * HW)        // 262144
#define TOTAL 8388608

// workspace layout (bytes)
#define EMBB_OFF  0                        // ushort[1024*256] bf16 = 512 KB
#define ENORM_OFF (512 * 1024)             // float[1024]
#define HIST_OFF  (ENORM_OFF + 4096)       // int[1024]
#define LOSS_OFF  (HIST_OFF + 4096)        // float accumulator

// round-to-nearest-even fp32 -> bf16 bits (inputs are finite)
__device__ __forceinline__ unsigned short f2bf(float x) {
    unsigned u = __builtin_bit_cast(unsigned, x);
    return (unsigned short)((u + 0x7fffu + ((u >> 16) & 1u)) >> 16);
}

// ---------------------------------------------------------------------------
// P: emb fp32 [1024][256] -> embB bf16 rows + enorm. 64 blocks x 256 thr,
// 16 threads per code row. Block 0 also zeroes hist + loss accumulator.
// ---------------------------------------------------------------------------
__global__ void prep_emb(const float* __restrict__ emb,
                         unsigned short* __restrict__ embB,
                         float* __restrict__ enorm,
                         int* __restrict__ hist,
                         float* __restrict__ lossAcc) {
    int t = threadIdx.x;
    int gid = blockIdx.x * 256 + t;        // 0..16383
    int row = gid >> 4, seg = gid & 15;
    const float4* e4 = (const float4*)(emb + (size_t)row * EDIM) + seg * 4;
    float4 a0 = e4[0], a1 = e4[1], a2 = e4[2], a3 = e4[3];
    float s = a0.x * a0.x + a0.y * a0.y + a0.z * a0.z + a0.w * a0.w
            + a1.x * a1.x + a1.y * a1.y + a1.z * a1.z + a1.w * a1.w
            + a2.x * a2.x + a2.y * a2.y + a2.z * a2.z + a2.w * a2.w
            + a3.x * a3.x + a3.y * a3.y + a3.z * a3.z + a3.w * a3.w;
    short8 v0, v1;
    v0[0] = (short)f2bf(a0.x); v0[1] = (short)f2bf(a0.y);
    v0[2] = (short)f2bf(a0.z); v0[3] = (short)f2bf(a0.w);
    v0[4] = (short)f2bf(a1.x); v0[5] = (short)f2bf(a1.y);
    v0[6] = (short)f2bf(a1.z); v0[7] = (short)f2bf(a1.w);
    v1[0] = (short)f2bf(a2.x); v1[1] = (short)f2bf(a2.y);
    v1[2] = (short)f2bf(a2.z); v1[3] = (short)f2bf(a2.w);
    v1[4] = (short)f2bf(a3.x); v1[5] = (short)f2bf(a3.y);
    v1[6] = (short)f2bf(a3.z); v1[7] = (short)f2bf(a3.w);
    *(short8*)&embB[(size_t)row * EDIM + seg * 16]     = v0;
    *(short8*)&embB[(size_t)row * EDIM + seg * 16 + 8] = v1;
    s += __shfl_xor(s, 1, 64);
    s += __shfl_xor(s, 2, 64);
    s += __shfl_xor(s, 4, 64);
    s += __shfl_xor(s, 8, 64);
    if (seg == 0) enorm[row] = s;
    if (blockIdx.x == 0) {                 // fold memset into this dispatch
        ((int4*)hist)[t] = (int4){0, 0, 0, 0};
        if (t == 0) lossAcc[0] = 0.f;
    }
}

// ---------------------------------------------------------------------------
// F: fused argmin + gather + loss + hist. Block = 64 positions, 256 threads
// (4 waves), grid 512 (= 2 blocks/CU). embB is L2-resident (512 KB bf16), so
// B fragments are read DIRECTLY from global in the main loop: no Bs LDS
// staging, no main-loop barriers (round-0 had 8 barrier-drained tiles; that
// barrier drain was the latency bottleneck — MfmaUtil 7%, HBM 10%, occ 19%).
// Wave (mw,nw): mw = 32-position half (A frags in regs), nw = 512-code half.
// The mw-pair of waves reads the same B lines near-lockstep -> L1/L2 hits.
// Epilogue unchanged: Es transpose-stage -> coalesced z_q write + loss.
// ---------------------------------------------------------------------------
__global__ __launch_bounds__(256, 2) void fused_kernel(
        const float* __restrict__ z, const float* __restrict__ emb,
        const unsigned short* __restrict__ embB, const float* __restrict__ enormG,
        float* __restrict__ zq, int* __restrict__ hist,
        float* __restrict__ lossAcc) {
    // union buffer: As 64x264 bf16 (33.8 KB) / Es 256x17 float4 (69.6 KB)
    __shared__ __align__(16) char smem[256 * 17 * 16];
    __shared__ float Ens[NE];
    __shared__ float rv[2][64];
    __shared__ int   ri[2][64];
    __shared__ int   idxm[64];

    unsigned short* As = (unsigned short*)smem;
    float4*         Es = (float4*)smem;
    float*         Esf = (float*)smem;

    int t = threadIdx.x;                   // 0..255
    int m0 = blockIdx.x * 64;
    int b = m0 >> 10, pb = m0 & 1023;
    const float* zb  = z  + (size_t)b * BSTRIDE + pb;
    float*       zqb = zq + (size_t)b * BSTRIDE + pb;

    for (int j = t; j < NE; j += 256) Ens[j] = enormG[j];

    {   // stage A: float4 loads along p, packed short8 LDS writes.
        // thread = (p-quad pq, 16-channel group cg), two halves of 8 channels.
        int pq = t & 15, cg = t >> 4;      // cg 0..15
        const float* zp = zb + pq * 4;
#pragma unroll
        for (int u = 0; u < 2; ++u) {
            int c0 = cg * 16 + u * 8;
            float4 zv[8];
#pragma unroll
            for (int v = 0; v < 8; ++v)
                zv[v] = *(const float4*)&zp[(size_t)(c0 + v) * HW];
#pragma unroll
            for (int j = 0; j < 4; ++j) {
                short8 w8;
#pragma unroll
                for (int v = 0; v < 8; ++v) {
                    float x = (j == 0) ? zv[v].x : (j == 1) ? zv[v].y
                            : (j == 2) ? zv[v].z : zv[v].w;
                    w8[v] = (short)f2bf(x);
                }
                *(short8*)&As[(pq * 4 + j) * 264 + c0] = w8;
            }
        }
    }
    __syncthreads();

    int w = t >> 6, l = t & 63, lm = l & 15, q = l >> 4;
    int mw = w >> 1, nw = w & 1;           // mw = 32-pos half, nw = 512-code half

    short8 A[2][8];
#pragma unroll
    for (int s = 0; s < 2; ++s)
#pragma unroll
        for (int ks = 0; ks < 8; ++ks)
            A[s][ks] = *(const short8*)&As[(mw * 32 + s * 16 + lm) * 264 + ks * 32 + q * 8];

    float bd[8]; int bi[8];
#pragma unroll
    for (int i = 0; i < 8; ++i) { bd[i] = FLT_MAX; bi[i] = 0x7fffffff; }

    // main loop: 32 col-frags of 16 codes each, B direct from global (L2).
    // Per iter: 8 independent 16B loads feed 16 MFMAs; no barriers.
    const short8* eB8 = (const short8*)embB;
#pragma unroll 2
    for (int ct = 0; ct < 32; ++ct) {
        int code = nw * 512 + ct * 16 + lm;
        const short8* bp = eB8 + (size_t)code * 32 + q;
        f32x4 a0a = {0,0,0,0}, a0b = {0,0,0,0};
        f32x4 a1a = {0,0,0,0}, a1b = {0,0,0,0};
#pragma unroll
        for (int ks = 0; ks < 8; ks += 2) {
            short8 Bv0 = bp[ks * 4];
            short8 Bv1 = bp[ks * 4 + 4];
            a0a = __builtin_amdgcn_mfma_f32_16x16x32_bf16(A[0][ks],     Bv0, a0a, 0, 0, 0);
            a1a = __builtin_amdgcn_mfma_f32_16x16x32_bf16(A[1][ks],     Bv0, a1a, 0, 0, 0);
            a0b = __builtin_amdgcn_mfma_f32_16x16x32_bf16(A[0][ks + 1], Bv1, a0b, 0, 0, 0);
            a1b = __builtin_amdgcn_mfma_f32_16x16x32_bf16(A[1][ks + 1], Bv1, a1b, 0, 0, 0);
        }
        float en = Ens[code];
#pragma unroll
        for (int r = 0; r < 4; ++r) {
            float d0 = en - 2.f * (a0a[r] + a0b[r]);
            if (d0 < bd[r])     { bd[r] = d0;     bi[r] = code; }
            float d1 = en - 2.f * (a1a[r] + a1b[r]);
            if (d1 < bd[4 + r]) { bd[4 + r] = d1; bi[4 + r] = code; }
        }
    }

    // reduce across the 16 code-columns (lanes sharing q)
#pragma unroll
    for (int off = 1; off < 16; off <<= 1) {
#pragma unroll
        for (int i = 0; i < 8; ++i) {
            float od = __shfl_xor(bd[i], off, 64);
            int   oi = __shfl_xor(bi[i], off, 64);
            if (od < bd[i] || (od == bd[i] && oi < bi[i])) { bd[i] = od; bi[i] = oi; }
        }
    }
    if (lm == 0) {
#pragma unroll
        for (int s = 0; s < 2; ++s)
#pragma unroll
            for (int r = 0; r < 4; ++r) {
                int p = mw * 32 + s * 16 + q * 4 + r;
                rv[nw][p] = bd[s * 4 + r];
                ri[nw][p] = bi[s * 4 + r];
            }
    }
    __syncthreads();
    if (t < 64) {
        float v0 = rv[0][t]; int i0 = ri[0][t];
        float v1 = rv[1][t]; int i1 = ri[1][t];
        int best = (v1 < v0 || (v1 == v0 && i1 < i0)) ? i1 : i0;
        idxm[t] = best;
        atomicAdd(&hist[best], 1);
    }
    __syncthreads();   // all waves past As reads; smem becomes Es

    {   // stage selected fp32 emb rows: position r, quarter qo (16 float4 each)
        int r = t >> 2, qo = t & 3;
        int kr = idxm[r];
        const float4* er = (const float4*)(emb + (size_t)kr * EDIM);
        int base = (r >> 2) * 4 + (r & 3);     // dword offset within c-row
#pragma unroll
        for (int u = 0; u < 16; ++u) {
            float4 v = er[qo * 16 + u];
            int c = (qo * 16 + u) * 4;
            Esf[(c + 0) * 68 + base] = v.x;
            Esf[(c + 1) * 68 + base] = v.y;
            Esf[(c + 2) * 68 + base] = v.z;
            Esf[(c + 3) * 68 + base] = v.w;
        }
    }
    __syncthreads();

    {   // z_q write + loss: thread = (p-quad, 16 channels)
        int pq = t & 15, cg2 = t >> 4;
        float ls = 0.f;
#pragma unroll 4
        for (int cc = 0; cc < 16; ++cc) {
            int c = cg2 * 16 + cc;
            float4 zv = *(const float4*)&zb[(size_t)c * HW + pq * 4];
            float4 ev = Es[c * 17 + pq];
            *(float4*)&zqb[(size_t)c * HW + pq * 4] = ev;
            float dx = ev.x - zv.x, dy = ev.y - zv.y;
            float dz = ev.z - zv.z, dw = ev.w - zv.w;
            ls += dx * dx + dy * dy + dz * dz + dw * dw;
        }
#pragma unroll
        for (int off = 32; off; off >>= 1) ls += __shfl_down(ls, off, 64);
        if ((t & 63) == 0) atomicAdd(lossAcc, ls);
    }
}

// ---------------------------------------------------------------------------
// Z: finalize loss + perplexity into d_out tail.
// ---------------------------------------------------------------------------
__global__ void finalize_kernel(const int* __restrict__ hist,
                                const float* __restrict__ lossAcc,
                                float* __restrict__ out) {
    __shared__ float wsum[4];
    int t = threadIdx.x;
    float s = 0.f;
    for (int j = t; j < NE; j += 256) {
        float p = (float)hist[j] * (1.0f / 32768.0f);
        s += p * logf(p + 1e-10f);
    }
#pragma unroll
    for (int off = 32; off; off >>= 1) s += __shfl_down(s, off, 64);
    if ((t & 63) == 0) wsum[t >> 6] = s;
    __syncthreads();
    if (t == 0) {
        float S = wsum[0] + wsum[1] + wsum[2] + wsum[3];
        out[TOTAL]     = 1.25f * lossAcc[0] / (float)TOTAL;
        out[TOTAL + 1] = expf(-S);
    }
}

extern "C" void kernel_launch(void* const* d_in, const int* in_sizes, int n_in,
                              void* d_out, int out_size, void* d_ws, size_t ws_size,
                              hipStream_t stream) {
    (void)in_sizes; (void)n_in; (void)out_size; (void)ws_size;
    const float* z   = (const float*)d_in[0];
    const float* emb = (const float*)d_in[1];
    float* out = (float*)d_out;
    char* ws = (char*)d_ws;
    unsigned short* embB = (unsigned short*)(ws + EMBB_OFF);
    float* enorm   = (float*)(ws + ENORM_OFF);
    int*   hist    = (int*)(ws + HIST_OFF);
    float* lossAcc = (float*)(ws + LOSS_OFF);

    prep_emb<<<64, 256, 0, stream>>>(emb, embB, enorm, hist, lossAcc);
    fused_kernel<<<512, 256, 0, stream>>>(z, emb, embB, enorm, out, hist, lossAcc);
    finalize_kernel<<<1, 256, 0, stream>>>(hist, lossAcc, out);
}